// Round 6
// baseline (579.058 us; speedup 1.0000x reference)
//
#include <hip/hip_runtime.h>
#include <math.h>

typedef unsigned short ushort_t;
typedef __attribute__((ext_vector_type(8))) short bf16x8;
typedef __attribute__((ext_vector_type(4))) float f32x4;

#define TOKENS 8192
#define DIMD   1024
#define TDIM   3072
#define HIDN   4096
#define NHEADS 16
#define HD     64

__device__ inline float bf2f(ushort_t h){ return __uint_as_float(((unsigned)h)<<16); }
__device__ inline ushort_t f2bf(float f){
  unsigned u = __float_as_uint(f);
  unsigned r = (u + 0x7fffu + ((u>>16)&1u)) >> 16;   // RNE
  return (ushort_t)r;
}
// tanh-form GELU via hw exp; |err vs erf-GELU| < 0.003 << bf16 quant noise
__device__ inline float gelu_f(float x){
  float u = 1.5957691216f * x * fmaf(0.044715f, x*x, 1.0f);
  return x / (1.0f + __expf(-u));
}

// async global->LDS, 16B/lane; LDS dest = wave-uniform base + lane*16
__device__ inline void glds16(const ushort_t* g, ushort_t* l){
  __builtin_amdgcn_global_load_lds(
      (const __attribute__((address_space(1))) void*)g,
      (__attribute__((address_space(3))) void*)l,
      16, 0, 0);
}

// ---------------------------------------------------------------- device bodies
__device__ inline void transpose_tile(const float* __restrict__ in,
                                      ushort_t* __restrict__ out,
                                      int R, int C, int cx, int ry,
                                      ushort_t* t /*64*65*/)
{
  const int c0 = cx*64, r0 = ry*64;
  for (int idx = threadIdx.x; idx < 4096; idx += 256) {
    int r = idx>>6, c = idx&63;
    t[r*65+c] = f2bf(in[(size_t)(r0+r)*C + c0+c]);
  }
  __syncthreads();
  for (int idx = threadIdx.x; idx < 4096; idx += 256) {
    int c = idx>>6, r = idx&63;
    out[(size_t)(c0+c)*R + r0+r] = t[r*65+c];
  }
}

__device__ inline void ln_row(const float* __restrict__ xin, int rowid,
                              const float* __restrict__ g,
                              const float* __restrict__ bta,
                              ushort_t* __restrict__ out,
                              float* rs /*8 floats*/)
{
  const int tid = threadIdx.x;
  const size_t base = (size_t)rowid * DIMD;
  float v[4];
  #pragma unroll
  for (int i=0;i<4;i++) v[i] = xin[base + tid + i*256];
  float s  = v[0]+v[1]+v[2]+v[3];
  float s2 = v[0]*v[0]+v[1]*v[1]+v[2]*v[2]+v[3]*v[3];
  #pragma unroll
  for (int off=32; off; off>>=1){ s += __shfl_xor(s, off); s2 += __shfl_xor(s2, off); }
  const int wave = tid>>6, lane = tid&63;
  if (lane==0){ rs[wave]=s; rs[4+wave]=s2; }
  __syncthreads();
  s  = rs[0]+rs[1]+rs[2]+rs[3];
  s2 = rs[4]+rs[5]+rs[6]+rs[7];
  const float mean = s * (1.f/DIMD);
  const float var  = s2 * (1.f/DIMD) - mean*mean;
  const float rstd = rsqrtf(var + 1e-6f);
  #pragma unroll
  for (int i=0;i<4;i++){
    int c = tid + i*256;
    out[base+c] = f2bf((v[i]-mean)*rstd*g[c] + bta[c]);
  }
}

// ------------------------------------------------ prep: LN1 + 4 weight transposes
__global__ __launch_bounds__(256)
void prep_kernel(const float* __restrict__ x,
                 const float* __restrict__ ln_g, const float* __restrict__ ln_b,
                 ushort_t* __restrict__ lnbuf,
                 const float* __restrict__ w_qkv,  ushort_t* __restrict__ wqkvT,
                 const float* __restrict__ w_proj, ushort_t* __restrict__ wprojT,
                 const float* __restrict__ w_fc1,  ushort_t* __restrict__ wfc1T,
                 const float* __restrict__ w_fc2,  ushort_t* __restrict__ wfc2T)
{
  __shared__ char smem[64*65*2];
  const int bid = blockIdx.x;
  if (bid < TOKENS) {
    ln_row(x, bid, ln_g, ln_b, lnbuf, (float*)smem);
    return;
  }
  int t = bid - TOKENS;
  ushort_t* ts = (ushort_t*)smem;
  if (t < 768)        transpose_tile(w_qkv,  wqkvT,  DIMD, TDIM, t%48, t/48, ts);
  else if (t < 1024){ t -= 768;  transpose_tile(w_proj, wprojT, DIMD, DIMD, t%16, t/16, ts); }
  else if (t < 2048){ t -= 1024; transpose_tile(w_fc1,  wfc1T,  DIMD, HIDN, t%64, t/64, ts); }
  else              { t -= 2048; transpose_tile(w_fc2,  wfc2T,  HIDN, DIMD, t%16, t/16, ts); }
}

// ---------------------------------------------------------------- layernorm (ln2)
__global__ __launch_bounds__(256)
void ln_kernel(const float* __restrict__ xin, const float* __restrict__ g,
               const float* __restrict__ bta, ushort_t* __restrict__ out)
{
  __shared__ float rs[8];
  ln_row(xin, blockIdx.x, g, bta, out, rs);
}

// ------------------------------------------------ GEMM 128x128 (m97 structure)
template<int RES, int OUTF, int ACT, int QKVW>
__global__ __launch_bounds__(256)
void gemm128(const ushort_t* __restrict__ A, const ushort_t* __restrict__ Bt,
             const float* __restrict__ bias, const float* __restrict__ res,
             void* __restrict__ out, int M, int N, int K)
{
  __shared__ ushort_t As[128*32];
  __shared__ ushort_t Bs[128*32];
  const int tid = threadIdx.x, wave = tid>>6, lane = tid&63;
  const int bm = blockIdx.y, bn = blockIdx.x;

  const int sr  = lane>>2;
  const int scw = ((lane&3) ^ (sr&3))*8;       // swizzled source chunk
  const ushort_t* Ag0 = A  + (size_t)(bm*128 + wave*32 + sr)*K + scw;
  const ushort_t* Ag1 = Ag0 + (size_t)16*K;
  const ushort_t* Bg0 = Bt + (size_t)(bn*128 + wave*32 + sr)*K + scw;
  const ushort_t* Bg1 = Bg0 + (size_t)16*K;
  ushort_t* Asw0 = &As[(wave*32)*32];
  ushort_t* Asw1 = &As[(wave*32+16)*32];
  ushort_t* Bsw0 = &Bs[(wave*32)*32];
  ushort_t* Bsw1 = &Bs[(wave*32+16)*32];

  f32x4 acc[4][4];
  #pragma unroll
  for (int m=0;m<4;m++)
    #pragma unroll
    for (int n=0;n<4;n++) acc[m][n] = (f32x4){0.f,0.f,0.f,0.f};

  const int row = lane&15, quad = lane>>4;
  const int mrow = (wave&1)*64, ncol = (wave>>1)*64;
  const int chsw = (quad ^ (row&3))*8;

  for (int k0=0; k0<K; k0+=32){
    __syncthreads();
    glds16(Ag0+k0, Asw0); glds16(Ag1+k0, Asw1);
    glds16(Bg0+k0, Bsw0); glds16(Bg1+k0, Bsw1);
    __syncthreads();
    bf16x8 af[4], bfr[4];
    #pragma unroll
    for (int m=0;m<4;m++) af[m]  = *(const bf16x8*)&As[(mrow+m*16+row)*32 + chsw];
    #pragma unroll
    for (int n=0;n<4;n++) bfr[n] = *(const bf16x8*)&Bs[(ncol+n*16+row)*32 + chsw];
    #pragma unroll
    for (int m=0;m<4;m++)
      #pragma unroll
      for (int n=0;n<4;n++)
        acc[m][n] = __builtin_amdgcn_mfma_f32_16x16x32_bf16(af[m], bfr[n], acc[m][n], 0,0,0);
  }

  const int r0 = bm*128 + mrow + quad*4;
  #pragma unroll
  for (int n=0;n<4;n++){
    const int gc = bn*128 + ncol + n*16 + row;
    const float bv = bias[gc];
    #pragma unroll
    for (int m=0;m<4;m++){
      #pragma unroll
      for (int r=0;r<4;r++){
        const int grow = r0 + m*16 + r;
        float v = acc[m][n][r] + bv;
        if (ACT) v = gelu_f(v);
        if (QKVW) {
          const int which = gc>>10, hh = (gc>>6)&15, d = gc&63;
          const int bb = grow>>10, nn = grow&1023;
          ((ushort_t*)out)[((size_t)(which*128 + bb*16 + hh)<<16) + nn*64 + d] = f2bf(v);
        } else {
          const size_t idx = (size_t)grow*N + gc;
          if (RES)  v += res[idx];
          if (OUTF) ((float*)out)[idx] = v;
          else      ((ushort_t*)out)[idx] = f2bf(v);
        }
      }
    }
  }
}

// ------------------------------------------------ GEMM 64x128 (4 blocks/CU for N=1024)
// Tile M=64, N=128; wave w computes 32x64 (mrow=(w&1)*32, ncol=(w>>1)*64).
template<int RES, int OUTF, int ACT>
__global__ __launch_bounds__(256)
void gemm64x128(const ushort_t* __restrict__ A, const ushort_t* __restrict__ Bt,
                const float* __restrict__ bias, const float* __restrict__ res,
                void* __restrict__ out, int M, int N, int K)
{
  __shared__ ushort_t As[64*32];
  __shared__ ushort_t Bs[128*32];
  const int tid = threadIdx.x, wave = tid>>6, lane = tid&63;
  const int bm = blockIdx.y, bn = blockIdx.x;

  const int sr  = lane>>2;
  const int scw = ((lane&3) ^ (sr&3))*8;
  // wave w stages A rows [w*16,+16) and B rows [w*32,+32)
  const ushort_t* Ag0 = A  + (size_t)(bm*64  + wave*16 + sr)*K + scw;
  const ushort_t* Bg0 = Bt + (size_t)(bn*128 + wave*32 + sr)*K + scw;
  const ushort_t* Bg1 = Bg0 + (size_t)16*K;
  ushort_t* Asw0 = &As[(wave*16)*32];
  ushort_t* Bsw0 = &Bs[(wave*32)*32];
  ushort_t* Bsw1 = &Bs[(wave*32+16)*32];

  f32x4 acc[2][4];
  #pragma unroll
  for (int m=0;m<2;m++)
    #pragma unroll
    for (int n=0;n<4;n++) acc[m][n] = (f32x4){0.f,0.f,0.f,0.f};

  const int row = lane&15, quad = lane>>4;
  const int mrow = (wave&1)*32, ncol = (wave>>1)*64;
  const int chsw = (quad ^ (row&3))*8;

  for (int k0=0; k0<K; k0+=32){
    __syncthreads();
    glds16(Ag0+k0, Asw0);
    glds16(Bg0+k0, Bsw0); glds16(Bg1+k0, Bsw1);
    __syncthreads();
    bf16x8 af[2], bfr[4];
    #pragma unroll
    for (int m=0;m<2;m++) af[m]  = *(const bf16x8*)&As[(mrow+m*16+row)*32 + chsw];
    #pragma unroll
    for (int n=0;n<4;n++) bfr[n] = *(const bf16x8*)&Bs[(ncol+n*16+row)*32 + chsw];
    #pragma unroll
    for (int m=0;m<2;m++)
      #pragma unroll
      for (int n=0;n<4;n++)
        acc[m][n] = __builtin_amdgcn_mfma_f32_16x16x32_bf16(af[m], bfr[n], acc[m][n], 0,0,0);
  }

  const int r0 = bm*64 + mrow + quad*4;
  #pragma unroll
  for (int n=0;n<4;n++){
    const int gc = bn*128 + ncol + n*16 + row;
    const float bv = bias[gc];
    #pragma unroll
    for (int m=0;m<2;m++){
      #pragma unroll
      for (int r=0;r<4;r++){
        const int grow = r0 + m*16 + r;
        float v = acc[m][n][r] + bv;
        if (ACT) v = gelu_f(v);
        const size_t idx = (size_t)grow*N + gc;
        if (RES)  v += res[idx];
        if (OUTF) ((float*)out)[idx] = v;
        else      ((ushort_t*)out)[idx] = f2bf(v);
      }
    }
  }
}

// ---------------------------------------------------------------- attention
#define AST 72
__global__ __launch_bounds__(256)
void attn_mfma(const ushort_t* __restrict__ qkv3, ushort_t* __restrict__ out)
{
  __shared__ ushort_t Ks[2][64*64];
  __shared__ ushort_t Vt[2][64*AST];
  __shared__ ushort_t Ps[4][16*AST];

  const int tid = threadIdx.x, wave = tid>>6, lane = tid&63;
  const int row = lane&15, quad = lane>>4;
  const int qt = blockIdx.x & 15;
  const int bh = blockIdx.x >> 4;
  const ushort_t* qp = qkv3 + ((size_t)bh<<16);
  const ushort_t* kp = qkv3 + ((size_t)(128+bh)<<16);
  const ushort_t* vp = qkv3 + ((size_t)(256+bh)<<16);

  const ushort_t* qrp = qp + (size_t)(qt*64 + wave*16 + row)*64 + quad*8;
  bf16x8 qa0 = *(const bf16x8*)(qrp);
  bf16x8 qa1 = *(const bf16x8*)(qrp + 32);

  const int krow = (lane>>3);
  const int kch  = ((lane&7) ^ krow)*8;

  f32x4 acc_o[4];
  #pragma unroll
  for (int nt=0;nt<4;nt++) acc_o[nt] = (f32x4){0.f,0.f,0.f,0.f};
  float lp[4] = {0.f,0.f,0.f,0.f};
  uint4 va[2];

  #pragma unroll
  for (int i=0;i<2;i++)
    glds16(kp + (size_t)(wave*16 + i*8 + krow)*64 + kch, &Ks[0][(wave*16+i*8)*64]);
  #pragma unroll
  for (int i=0;i<2;i++){
    int idx=i*256+tid, ch=idx>>6, key=idx&63;
    va[i] = *(const uint4*)(vp + (size_t)key*64 + ch*8);
  }
  #pragma unroll
  for (int i=0;i<2;i++){
    int idx=i*256+tid, ch=idx>>6, key=idx&63;
    ushort_t tmp[8]; *(uint4*)tmp = va[i];
    #pragma unroll
    for (int j=0;j<8;j++) Vt[0][(ch*8+j)*AST + key] = tmp[j];
  }

  for (int jt=0; jt<16; ++jt){
    const int p = jt&1;
    __syncthreads();
    if (jt<15){
      #pragma unroll
      for (int i=0;i<2;i++)
        glds16(kp + (size_t)((jt+1)*64 + wave*16 + i*8 + krow)*64 + kch,
               &Ks[1-p][(wave*16+i*8)*64]);
      #pragma unroll
      for (int i=0;i<2;i++){
        int idx=i*256+tid, ch=idx>>6, key=idx&63;
        va[i] = *(const uint4*)(vp + (size_t)((jt+1)*64+key)*64 + ch*8);
      }
    }

    #pragma unroll
    for (int ct=0;ct<4;ct++){
      const int key = ct*16 + row;
      f32x4 s = (f32x4){0.f,0.f,0.f,0.f};
      bf16x8 b0 = *(const bf16x8*)&Ks[p][key*64 + ((quad   ^(row&7))*8)];
      bf16x8 b1 = *(const bf16x8*)&Ks[p][key*64 + (((quad+4)^(row&7))*8)];
      s = __builtin_amdgcn_mfma_f32_16x16x32_bf16(qa0, b0, s, 0,0,0);
      s = __builtin_amdgcn_mfma_f32_16x16x32_bf16(qa1, b1, s, 0,0,0);
      #pragma unroll
      for (int r=0;r<4;r++){
        float pr = __expf(fmaf(s[r], 0.125f, -3.0f));
        lp[r] += pr;
        Ps[wave][(quad*4+r)*AST + ct*16 + row] = f2bf(pr);
      }
    }

    bf16x8 pa0 = *(const bf16x8*)&Ps[wave][row*AST + quad*8];
    bf16x8 pa1 = *(const bf16x8*)&Ps[wave][row*AST + 32 + quad*8];
    #pragma unroll
    for (int nt=0;nt<4;nt++){
      bf16x8 vb0 = *(const bf16x8*)&Vt[p][(nt*16+row)*AST + quad*8];
      bf16x8 vb1 = *(const bf16x8*)&Vt[p][(nt*16+row)*AST + 32 + quad*8];
      acc_o[nt] = __builtin_amdgcn_mfma_f32_16x16x32_bf16(pa0, vb0, acc_o[nt], 0,0,0);
      acc_o[nt] = __builtin_amdgcn_mfma_f32_16x16x32_bf16(pa1, vb1, acc_o[nt], 0,0,0);
    }

    if (jt<15){
      #pragma unroll
      for (int i=0;i<2;i++){
        int idx=i*256+tid, ch=idx>>6, key=idx&63;
        ushort_t tmp[8]; *(uint4*)tmp = va[i];
        #pragma unroll
        for (int j=0;j<8;j++) Vt[1-p][(ch*8+j)*AST + key] = tmp[j];
      }
    }
  }

  #pragma unroll
  for (int r=0;r<4;r++){
    float l = lp[r];
    l += __shfl_xor(l,1); l += __shfl_xor(l,2);
    l += __shfl_xor(l,4); l += __shfl_xor(l,8);
    lp[r] = l;
  }
  const int b = bh>>4, h = bh&15;
  #pragma unroll
  for (int nt=0;nt<4;nt++){
    #pragma unroll
    for (int r=0;r<4;r++){
      size_t o = (size_t)(b*1024 + qt*64 + wave*16 + quad*4 + r)*DIMD
               + h*64 + nt*16 + row;
      out[o] = f2bf(acc_o[nt][r] / lp[r]);
    }
  }
}

// ---------------------------------------------------------------- launch
extern "C" void kernel_launch(void* const* d_in, const int* in_sizes, int n_in,
                              void* d_out, int out_size, void* d_ws, size_t ws_size,
                              hipStream_t stream)
{
  const float* x      = (const float*)d_in[0];
  const float* ln_g   = (const float*)d_in[1];
  const float* ln_b   = (const float*)d_in[2];
  const float* w_qkv  = (const float*)d_in[3];
  const float* b_qkv  = (const float*)d_in[4];
  const float* w_proj = (const float*)d_in[5];
  const float* b_proj = (const float*)d_in[6];
  const float* w_fc1  = (const float*)d_in[7];
  const float* b_fc1  = (const float*)d_in[8];
  const float* w_fc2  = (const float*)d_in[9];
  const float* b_fc2  = (const float*)d_in[10];

  char* ws = (char*)d_ws;
  ushort_t* wqkvT  = (ushort_t*)(ws + 0);
  ushort_t* wprojT = (ushort_t*)(ws + 6291456);
  ushort_t* wfc1T  = (ushort_t*)(ws + 8388608);
  ushort_t* wfc2T  = (ushort_t*)(ws + 16777216);
  ushort_t* lnbuf  = (ushort_t*)(ws + 25165824);
  ushort_t* qkv3   = (ushort_t*)(ws + 41943040);
  float*    hbuf   = (float*)   (ws + 41943040);
  ushort_t* gbuf   = (ushort_t*)(ws + 75497472);

  // LN1 + all weight transposes fused (mutually independent)
  prep_kernel<<<TOKENS + 3072, 256, 0, stream>>>(
      x, ln_g, ln_b, lnbuf,
      w_qkv, wqkvT, w_proj, wprojT, w_fc1, wfc1T, w_fc2, wfc2T);

  gemm128<0,0,0,1><<<dim3(TDIM/128, TOKENS/128), 256, 0, stream>>>(
      lnbuf, wqkvT, b_qkv, nullptr, qkv3, TOKENS, TDIM, DIMD);
  attn_mfma<<<128*16, 256, 0, stream>>>(qkv3, lnbuf);
  gemm64x128<1,1,0><<<dim3(DIMD/128, TOKENS/64), 256, 0, stream>>>(
      lnbuf, wprojT, b_proj, x, hbuf, TOKENS, DIMD, DIMD);
  ln_kernel<<<TOKENS, 256, 0, stream>>>(hbuf, ln_g, ln_b, lnbuf);
  gemm128<0,0,1,0><<<dim3(HIDN/128, TOKENS/128), 256, 0, stream>>>(
      lnbuf, wfc1T, b_fc1, nullptr, gbuf, TOKENS, HIDN, DIMD);
  gemm64x128<1,1,0><<<dim3(DIMD/128, TOKENS/64), 256, 0, stream>>>(
      gbuf, wfc2T, b_fc2, hbuf, d_out, TOKENS, DIMD, HIDN);
}

// Round 7
// 537.588 us; speedup vs baseline: 1.0771x; 1.0771x over previous
//
#include <hip/hip_runtime.h>
#include <math.h>

typedef unsigned short ushort_t;
typedef __attribute__((ext_vector_type(8))) short bf16x8;
typedef __attribute__((ext_vector_type(4))) float f32x4;

#define TOKENS 8192
#define DIMD   1024
#define TDIM   3072
#define HIDN   4096
#define NHEADS 16
#define HD     64

__device__ inline float bf2f(ushort_t h){ return __uint_as_float(((unsigned)h)<<16); }
__device__ inline ushort_t f2bf(float f){
  unsigned u = __float_as_uint(f);
  unsigned r = (u + 0x7fffu + ((u>>16)&1u)) >> 16;   // RNE
  return (ushort_t)r;
}
// tanh-form GELU via hw exp; |err vs erf-GELU| < 0.003 << bf16 quant noise
__device__ inline float gelu_f(float x){
  float u = 1.5957691216f * x * fmaf(0.044715f, x*x, 1.0f);
  return x / (1.0f + __expf(-u));
}

// async global->LDS, 16B/lane; LDS dest = wave-uniform base + lane*16
__device__ inline void glds16(const ushort_t* g, ushort_t* l){
  __builtin_amdgcn_global_load_lds(
      (const __attribute__((address_space(1))) void*)g,
      (__attribute__((address_space(3))) void*)l,
      16, 0, 0);
}

// ---------------------------------------------------------------- device bodies
__device__ inline void transpose_tile(const float* __restrict__ in,
                                      ushort_t* __restrict__ out,
                                      int R, int C, int cx, int ry,
                                      ushort_t* t /*64*65*/)
{
  const int c0 = cx*64, r0 = ry*64;
  for (int idx = threadIdx.x; idx < 4096; idx += 256) {
    int r = idx>>6, c = idx&63;
    t[r*65+c] = f2bf(in[(size_t)(r0+r)*C + c0+c]);
  }
  __syncthreads();
  for (int idx = threadIdx.x; idx < 4096; idx += 256) {
    int c = idx>>6, r = idx&63;
    out[(size_t)(c0+c)*R + r0+r] = t[r*65+c];
  }
}

__device__ inline void ln_row(const float* __restrict__ xin, int rowid,
                              const float* __restrict__ g,
                              const float* __restrict__ bta,
                              ushort_t* __restrict__ out,
                              float* rs /*8 floats*/)
{
  const int tid = threadIdx.x;
  const size_t base = (size_t)rowid * DIMD;
  float v[4];
  #pragma unroll
  for (int i=0;i<4;i++) v[i] = xin[base + tid + i*256];
  float s  = v[0]+v[1]+v[2]+v[3];
  float s2 = v[0]*v[0]+v[1]*v[1]+v[2]*v[2]+v[3]*v[3];
  #pragma unroll
  for (int off=32; off; off>>=1){ s += __shfl_xor(s, off); s2 += __shfl_xor(s2, off); }
  const int wave = tid>>6, lane = tid&63;
  if (lane==0){ rs[wave]=s; rs[4+wave]=s2; }
  __syncthreads();
  s  = rs[0]+rs[1]+rs[2]+rs[3];
  s2 = rs[4]+rs[5]+rs[6]+rs[7];
  const float mean = s * (1.f/DIMD);
  const float var  = s2 * (1.f/DIMD) - mean*mean;
  const float rstd = rsqrtf(var + 1e-6f);
  #pragma unroll
  for (int i=0;i<4;i++){
    int c = tid + i*256;
    out[base+c] = f2bf((v[i]-mean)*rstd*g[c] + bta[c]);
  }
}

// ------------------------------------------------ prep: LN1 + 4 weight transposes
__global__ __launch_bounds__(256)
void prep_kernel(const float* __restrict__ x,
                 const float* __restrict__ ln_g, const float* __restrict__ ln_b,
                 ushort_t* __restrict__ lnbuf,
                 const float* __restrict__ w_qkv,  ushort_t* __restrict__ wqkvT,
                 const float* __restrict__ w_proj, ushort_t* __restrict__ wprojT,
                 const float* __restrict__ w_fc1,  ushort_t* __restrict__ wfc1T,
                 const float* __restrict__ w_fc2,  ushort_t* __restrict__ wfc2T)
{
  __shared__ char smem[64*65*2];
  const int bid = blockIdx.x;
  if (bid < TOKENS) {
    ln_row(x, bid, ln_g, ln_b, lnbuf, (float*)smem);
    return;
  }
  int t = bid - TOKENS;
  ushort_t* ts = (ushort_t*)smem;
  if (t < 768)        transpose_tile(w_qkv,  wqkvT,  DIMD, TDIM, t%48, t/48, ts);
  else if (t < 1024){ t -= 768;  transpose_tile(w_proj, wprojT, DIMD, DIMD, t%16, t/16, ts); }
  else if (t < 2048){ t -= 1024; transpose_tile(w_fc1,  wfc1T,  DIMD, HIDN, t%64, t/64, ts); }
  else              { t -= 2048; transpose_tile(w_fc2,  wfc2T,  HIDN, DIMD, t%16, t/16, ts); }
}

// ---------------------------------------------------------------- layernorm (ln2)
__global__ __launch_bounds__(256)
void ln_kernel(const float* __restrict__ xin, const float* __restrict__ g,
               const float* __restrict__ bta, ushort_t* __restrict__ out)
{
  __shared__ float rs[8];
  ln_row(xin, blockIdx.x, g, bta, out, rs);
}

// ------------------------------------------------ GEMM 128x128, pipelined K-loop
// Double-buffered LDS; ONE barrier per k-step; DMA for tile k+1 issued AFTER the
// barrier (into the buffer all waves just finished reading), so the barrier's
// vmcnt(0) drain waits only for DMAs issued a full compute-phase earlier.
template<int RES, int OUTF, int ACT, int QKVW>
__global__ __launch_bounds__(256)
void gemm128(const ushort_t* __restrict__ A, const ushort_t* __restrict__ Bt,
             const float* __restrict__ bias, const float* __restrict__ res,
             void* __restrict__ out, int M, int N, int K)
{
  __shared__ ushort_t As[2][128*32];
  __shared__ ushort_t Bs[2][128*32];
  const int tid = threadIdx.x, wave = tid>>6, lane = tid&63;
  const int bm = blockIdx.y, bn = blockIdx.x;

  const int sr  = lane>>2;
  const int scw = ((lane&3) ^ (sr&3))*8;       // swizzled source chunk
  const ushort_t* Ag0 = A  + (size_t)(bm*128 + wave*32 + sr)*K + scw;
  const ushort_t* Ag1 = Ag0 + (size_t)16*K;
  const ushort_t* Bg0 = Bt + (size_t)(bn*128 + wave*32 + sr)*K + scw;
  const ushort_t* Bg1 = Bg0 + (size_t)16*K;
  const int aw0 = (wave*32)*32, aw1 = (wave*32+16)*32;

  // prologue: tile 0 -> buffer 0
  glds16(Ag0, &As[0][aw0]); glds16(Ag1, &As[0][aw1]);
  glds16(Bg0, &Bs[0][aw0]); glds16(Bg1, &Bs[0][aw1]);

  f32x4 acc[4][4];
  #pragma unroll
  for (int m=0;m<4;m++)
    #pragma unroll
    for (int n=0;n<4;n++) acc[m][n] = (f32x4){0.f,0.f,0.f,0.f};

  const int row = lane&15, quad = lane>>4;
  const int mrow = (wave&1)*64, ncol = (wave>>1)*64;
  const int chsw = (quad ^ (row&3))*8;

  const int NK = K>>5;
  for (int kt=0; kt<NK; ++kt){
    const int p = kt&1;
    __syncthreads();              // drains own tile-kt DMAs (issued last iter) + joins
    if (kt+1 < NK){
      const int k1 = (kt+1)<<5;
      glds16(Ag0+k1, &As[1-p][aw0]); glds16(Ag1+k1, &As[1-p][aw1]);
      glds16(Bg0+k1, &Bs[1-p][aw0]); glds16(Bg1+k1, &Bs[1-p][aw1]);
    }
    bf16x8 af[4], bfr[4];
    #pragma unroll
    for (int m=0;m<4;m++) af[m]  = *(const bf16x8*)&As[p][(mrow+m*16+row)*32 + chsw];
    #pragma unroll
    for (int n=0;n<4;n++) bfr[n] = *(const bf16x8*)&Bs[p][(ncol+n*16+row)*32 + chsw];
    #pragma unroll
    for (int m=0;m<4;m++)
      #pragma unroll
      for (int n=0;n<4;n++)
        acc[m][n] = __builtin_amdgcn_mfma_f32_16x16x32_bf16(af[m], bfr[n], acc[m][n], 0,0,0);
  }

  const int r0 = bm*128 + mrow + quad*4;   // C/D: col=lane&15, row=quad*4+r
  #pragma unroll
  for (int n=0;n<4;n++){
    const int gc = bn*128 + ncol + n*16 + row;
    const float bv = bias[gc];
    #pragma unroll
    for (int m=0;m<4;m++){
      #pragma unroll
      for (int r=0;r<4;r++){
        const int grow = r0 + m*16 + r;
        float v = acc[m][n][r] + bv;
        if (ACT) v = gelu_f(v);
        if (QKVW) {
          const int which = gc>>10, hh = (gc>>6)&15, d = gc&63;
          const int bb = grow>>10, nn = grow&1023;
          ((ushort_t*)out)[((size_t)(which*128 + bb*16 + hh)<<16) + nn*64 + d] = f2bf(v);
        } else {
          const size_t idx = (size_t)grow*N + gc;
          if (RES)  v += res[idx];
          if (OUTF) ((float*)out)[idx] = v;
          else      ((ushort_t*)out)[idx] = f2bf(v);
        }
      }
    }
  }
}

// ---------------------------------------------------------------- attention
#define AST 72
__global__ __launch_bounds__(256)
void attn_mfma(const ushort_t* __restrict__ qkv3, ushort_t* __restrict__ out)
{
  __shared__ ushort_t Ks[2][64*64];
  __shared__ ushort_t Vt[2][64*AST];
  __shared__ ushort_t Ps[4][16*AST];

  const int tid = threadIdx.x, wave = tid>>6, lane = tid&63;
  const int row = lane&15, quad = lane>>4;
  const int qt = blockIdx.x & 15;
  const int bh = blockIdx.x >> 4;
  const ushort_t* qp = qkv3 + ((size_t)bh<<16);
  const ushort_t* kp = qkv3 + ((size_t)(128+bh)<<16);
  const ushort_t* vp = qkv3 + ((size_t)(256+bh)<<16);

  const ushort_t* qrp = qp + (size_t)(qt*64 + wave*16 + row)*64 + quad*8;
  bf16x8 qa0 = *(const bf16x8*)(qrp);
  bf16x8 qa1 = *(const bf16x8*)(qrp + 32);

  const int krow = (lane>>3);
  const int kch  = ((lane&7) ^ krow)*8;

  f32x4 acc_o[4];
  #pragma unroll
  for (int nt=0;nt<4;nt++) acc_o[nt] = (f32x4){0.f,0.f,0.f,0.f};
  float lp[4] = {0.f,0.f,0.f,0.f};
  uint4 va[2];

  #pragma unroll
  for (int i=0;i<2;i++)
    glds16(kp + (size_t)(wave*16 + i*8 + krow)*64 + kch, &Ks[0][(wave*16+i*8)*64]);
  #pragma unroll
  for (int i=0;i<2;i++){
    int idx=i*256+tid, ch=idx>>6, key=idx&63;
    va[i] = *(const uint4*)(vp + (size_t)key*64 + ch*8);
  }
  #pragma unroll
  for (int i=0;i<2;i++){
    int idx=i*256+tid, ch=idx>>6, key=idx&63;
    ushort_t tmp[8]; *(uint4*)tmp = va[i];
    #pragma unroll
    for (int j=0;j<8;j++) Vt[0][(ch*8+j)*AST + key] = tmp[j];
  }

  for (int jt=0; jt<16; ++jt){
    const int p = jt&1;
    __syncthreads();
    if (jt<15){
      #pragma unroll
      for (int i=0;i<2;i++)
        glds16(kp + (size_t)((jt+1)*64 + wave*16 + i*8 + krow)*64 + kch,
               &Ks[1-p][(wave*16+i*8)*64]);
      #pragma unroll
      for (int i=0;i<2;i++){
        int idx=i*256+tid, ch=idx>>6, key=idx&63;
        va[i] = *(const uint4*)(vp + (size_t)((jt+1)*64+key)*64 + ch*8);
      }
    }

    #pragma unroll
    for (int ct=0;ct<4;ct++){
      const int key = ct*16 + row;
      f32x4 s = (f32x4){0.f,0.f,0.f,0.f};
      bf16x8 b0 = *(const bf16x8*)&Ks[p][key*64 + ((quad   ^(row&7))*8)];
      bf16x8 b1 = *(const bf16x8*)&Ks[p][key*64 + (((quad+4)^(row&7))*8)];
      s = __builtin_amdgcn_mfma_f32_16x16x32_bf16(qa0, b0, s, 0,0,0);
      s = __builtin_amdgcn_mfma_f32_16x16x32_bf16(qa1, b1, s, 0,0,0);
      #pragma unroll
      for (int r=0;r<4;r++){
        float pr = __expf(fmaf(s[r], 0.125f, -3.0f));
        lp[r] += pr;
        Ps[wave][(quad*4+r)*AST + ct*16 + row] = f2bf(pr);
      }
    }

    bf16x8 pa0 = *(const bf16x8*)&Ps[wave][row*AST + quad*8];
    bf16x8 pa1 = *(const bf16x8*)&Ps[wave][row*AST + 32 + quad*8];
    #pragma unroll
    for (int nt=0;nt<4;nt++){
      bf16x8 vb0 = *(const bf16x8*)&Vt[p][(nt*16+row)*AST + quad*8];
      bf16x8 vb1 = *(const bf16x8*)&Vt[p][(nt*16+row)*AST + 32 + quad*8];
      acc_o[nt] = __builtin_amdgcn_mfma_f32_16x16x32_bf16(pa0, vb0, acc_o[nt], 0,0,0);
      acc_o[nt] = __builtin_amdgcn_mfma_f32_16x16x32_bf16(pa1, vb1, acc_o[nt], 0,0,0);
    }

    if (jt<15){
      #pragma unroll
      for (int i=0;i<2;i++){
        int idx=i*256+tid, ch=idx>>6, key=idx&63;
        ushort_t tmp[8]; *(uint4*)tmp = va[i];
        #pragma unroll
        for (int j=0;j<8;j++) Vt[1-p][(ch*8+j)*AST + key] = tmp[j];
      }
    }
  }

  #pragma unroll
  for (int r=0;r<4;r++){
    float l = lp[r];
    l += __shfl_xor(l,1); l += __shfl_xor(l,2);
    l += __shfl_xor(l,4); l += __shfl_xor(l,8);
    lp[r] = l;
  }
  const int b = bh>>4, h = bh&15;
  #pragma unroll
  for (int nt=0;nt<4;nt++){
    #pragma unroll
    for (int r=0;r<4;r++){
      size_t o = (size_t)(b*1024 + qt*64 + wave*16 + quad*4 + r)*DIMD
               + h*64 + nt*16 + row;
      out[o] = f2bf(acc_o[nt][r] / lp[r]);
    }
  }
}

// ---------------------------------------------------------------- launch
extern "C" void kernel_launch(void* const* d_in, const int* in_sizes, int n_in,
                              void* d_out, int out_size, void* d_ws, size_t ws_size,
                              hipStream_t stream)
{
  const float* x      = (const float*)d_in[0];
  const float* ln_g   = (const float*)d_in[1];
  const float* ln_b   = (const float*)d_in[2];
  const float* w_qkv  = (const float*)d_in[3];
  const float* b_qkv  = (const float*)d_in[4];
  const float* w_proj = (const float*)d_in[5];
  const float* b_proj = (const float*)d_in[6];
  const float* w_fc1  = (const float*)d_in[7];
  const float* b_fc1  = (const float*)d_in[8];
  const float* w_fc2  = (const float*)d_in[9];
  const float* b_fc2  = (const float*)d_in[10];

  char* ws = (char*)d_ws;
  ushort_t* wqkvT  = (ushort_t*)(ws + 0);
  ushort_t* wprojT = (ushort_t*)(ws + 6291456);
  ushort_t* wfc1T  = (ushort_t*)(ws + 8388608);
  ushort_t* wfc2T  = (ushort_t*)(ws + 16777216);
  ushort_t* lnbuf  = (ushort_t*)(ws + 25165824);
  ushort_t* qkv3   = (ushort_t*)(ws + 41943040);
  float*    hbuf   = (float*)   (ws + 41943040);
  ushort_t* gbuf   = (ushort_t*)(ws + 75497472);

  prep_kernel<<<TOKENS + 3072, 256, 0, stream>>>(
      x, ln_g, ln_b, lnbuf,
      w_qkv, wqkvT, w_proj, wprojT, w_fc1, wfc1T, w_fc2, wfc2T);

  gemm128<0,0,0,1><<<dim3(TDIM/128, TOKENS/128), 256, 0, stream>>>(
      lnbuf, wqkvT, b_qkv, nullptr, qkv3, TOKENS, TDIM, DIMD);
  attn_mfma<<<128*16, 256, 0, stream>>>(qkv3, lnbuf);
  gemm128<1,1,0,0><<<dim3(DIMD/128, TOKENS/128), 256, 0, stream>>>(
      lnbuf, wprojT, b_proj, x, hbuf, TOKENS, DIMD, DIMD);
  ln_kernel<<<TOKENS, 256, 0, stream>>>(hbuf, ln_g, ln_b, lnbuf);
  gemm128<0,0,1,0><<<dim3(HIDN/128, TOKENS/128), 256, 0, stream>>>(
      lnbuf, wfc1T, b_fc1, nullptr, gbuf, TOKENS, HIDN, DIMD);
  gemm128<1,1,0,0><<<dim3(DIMD/128, TOKENS/128), 256, 0, stream>>>(
      gbuf, wfc2T, b_fc2, hbuf, d_out, TOKENS, DIMD, HIDN);
}